// Round 1
// baseline (902.794 us; speedup 1.0000x reference)
//
#include <hip/hip_runtime.h>
#include <hip/hip_bf16.h>
#include <math.h>

// Problem constants
#define M_ 2048
#define K_ 1024
#define V_ 50000
#define CV_ 120
#define NC_ (V_ + CV_)   // 50120 out row stride
#define S_ 100
#define B_ 32
#define PAD_IDX_ 1

// GEMM tiling
#define BM 128
#define BN 128
#define BK 32
#define LDST 40   // LDS row stride in bf16 elements (BK + 8 pad)

typedef float f32x4 __attribute__((ext_vector_type(4)));
typedef __bf16 bf16x2 __attribute__((ext_vector_type(2)));
typedef __bf16 bf16x4 __attribute__((ext_vector_type(4)));
typedef __bf16 bf16x8 __attribute__((ext_vector_type(8)));

// ---------------------------------------------------------------------------
// copy[n] = sigmoid(hidden[n,:] . w_copy + b_copy)
// one wave per row, 4 rows per 256-thread block
__global__ __launch_bounds__(256)
void k_copy(const float* __restrict__ hidden, const float* __restrict__ w_copy,
            const float* __restrict__ b_copy, float* __restrict__ cvec)
{
    int n = blockIdx.x * 4 + (threadIdx.x >> 6);
    int lane = threadIdx.x & 63;
    const float* h = hidden + (size_t)n * K_;
    float s = 0.f;
#pragma unroll
    for (int i = 0; i < 4; ++i) {       // 4 float4 per lane: 64*4*4 = 1024
        f32x4 hv = *(const f32x4*)(h + (lane + 64 * i) * 4);
        f32x4 wv = *(const f32x4*)(w_copy + (lane + 64 * i) * 4);
        s += hv[0] * wv[0] + hv[1] * wv[1] + hv[2] * wv[2] + hv[3] * wv[3];
    }
#pragma unroll
    for (int off = 32; off; off >>= 1) s += __shfl_down(s, off);
    if (lane == 0) cvec[n] = 1.f / (1.f + __expf(-(s + b_copy[0])));
}

// ---------------------------------------------------------------------------
// GEMM: out[m, c] = exp(hidden[m,:] @ W[:,c] + b[c]) for c < V (PAD col -> 0)
__global__ __launch_bounds__(256, 2)
void k_gemm_exp(const float* __restrict__ A, const float* __restrict__ W,
                const float* __restrict__ bias, float* __restrict__ out)
{
    __shared__ __bf16 lA[BM * LDST];
    __shared__ __bf16 lB[BN * LDST];

    const int tid  = threadIdx.x;
    const int lane = tid & 63;
    const int wid  = tid >> 6;
    const int wm   = wid >> 1;   // wave row 0..1
    const int wn   = wid & 1;    // wave col 0..1

    const int m0 = blockIdx.y * BM;
    const int n0 = blockIdx.x * BN;

    f32x4 acc[4][4] = {};

    for (int k0 = 0; k0 < K_; k0 += BK) {
        // ---- stage A tile: [BM][BK] f32 -> bf16, row-major, stride LDST
#pragma unroll
        for (int it = 0; it < 4; ++it) {
            int f   = tid + 256 * it;     // 0..1023 float4 id
            int row = f >> 3;             // BK/4 = 8 float4 per row
            int c4  = f & 7;
            f32x4 v = *(const f32x4*)(A + (size_t)(m0 + row) * K_ + k0 + c4 * 4);
            bf16x4 h;
            h[0] = (__bf16)v[0]; h[1] = (__bf16)v[1];
            h[2] = (__bf16)v[2]; h[3] = (__bf16)v[3];
            *(bf16x4*)(&lA[row * LDST + c4 * 4]) = h;
        }
        // ---- stage B tile transposed: global [BK][BN] -> lds [col][k]
        // chunk = (k-pair p, col-quad c4): 2 float4 loads, 4 packed b32 writes
#pragma unroll
        for (int it = 0; it < 2; ++it) {
            int ch = tid + 256 * it;      // 0..511
            int c4 = ch & 31;
            int p  = ch >> 5;             // k-pair 0..15
            int gc = n0 + c4 * 4;
            f32x4 v0 = {}, v1 = {};
            if (gc < V_) {                // V_-n0 is a multiple of 4 -> exact
                v0 = *(const f32x4*)(W + (size_t)(k0 + 2 * p) * V_ + gc);
                v1 = *(const f32x4*)(W + (size_t)(k0 + 2 * p + 1) * V_ + gc);
            }
#pragma unroll
            for (int i = 0; i < 4; ++i) {
                int c = c4 * 4 + i;
                int sp = p ^ (((c >> 2) & 3) << 2);   // 16B-granule XOR swizzle
                bf16x2 pk;
                pk[0] = (__bf16)v0[i];
                pk[1] = (__bf16)v1[i];
                *(bf16x2*)(&lB[c * LDST + sp * 2]) = pk;
            }
        }
        __syncthreads();

        // ---- fragments
        bf16x8 fa[4], fb[4];
#pragma unroll
        for (int mf = 0; mf < 4; ++mf) {
            int row = wm * 64 + mf * 16 + (lane & 15);
            fa[mf] = *(const bf16x8*)(&lA[row * LDST + (lane >> 4) * 8]);
        }
#pragma unroll
        for (int nf = 0; nf < 4; ++nf) {
            int col = wn * 64 + nf * 16 + (lane & 15);
            int g   = (lane >> 4) ^ ((col >> 2) & 3); // undo swizzle
            fb[nf] = *(const bf16x8*)(&lB[col * LDST + g * 8]);
        }
#pragma unroll
        for (int mf = 0; mf < 4; ++mf)
#pragma unroll
            for (int nf = 0; nf < 4; ++nf)
                acc[mf][nf] = __builtin_amdgcn_mfma_f32_16x16x32_bf16(
                    fa[mf], fb[nf], acc[mf][nf], 0, 0, 0);
        __syncthreads();
    }

    // ---- epilogue: exp + store (D layout: col = lane&15, row = (lane>>4)*4+r)
    const int rbase = m0 + wm * 64;
    const int cbase = n0 + wn * 64;
#pragma unroll
    for (int nf = 0; nf < 4; ++nf) {
        int gcol = cbase + nf * 16 + (lane & 15);
        if (gcol < V_) {
            float bb = bias[gcol];
#pragma unroll
            for (int mf = 0; mf < 4; ++mf) {
#pragma unroll
                for (int r = 0; r < 4; ++r) {
                    int grow = rbase + mf * 16 + (lane >> 4) * 4 + r;
                    float logit = acc[mf][nf][r] + bb;
                    float e = (gcol == PAD_IDX_) ? 0.0f : __expf(logit);
                    out[(size_t)grow * NC_ + gcol] = e;
                }
            }
        }
    }
}

// ---------------------------------------------------------------------------
// scale[n] = (1 - copy[n]) / sum_c out[n, c]
__global__ __launch_bounds__(256)
void k_rowsum(const float* __restrict__ out, const float* __restrict__ cvec,
              float* __restrict__ scale)
{
    int n = blockIdx.x;
    const float* row = out + (size_t)n * NC_;
    float s = 0.f;
    for (int i = threadIdx.x; i < V_ / 4; i += 256) {
        f32x4 v = *(const f32x4*)(row + i * 4);
        s += v[0] + v[1] + v[2] + v[3];
    }
#pragma unroll
    for (int off = 32; off; off >>= 1) s += __shfl_down(s, off);
    __shared__ float ws4[4];
    if ((threadIdx.x & 63) == 0) ws4[threadIdx.x >> 6] = s;
    __syncthreads();
    if (threadIdx.x == 0) {
        float t = ws4[0] + ws4[1] + ws4[2] + ws4[3];
        scale[n] = (1.f - cvec[n]) / t;
    }
}

// ---------------------------------------------------------------------------
// out[n, 0:V] *= scale[n]
__global__ __launch_bounds__(256)
void k_scale(float* __restrict__ out, const float* __restrict__ scale)
{
    int n = blockIdx.x;
    float sc = scale[n];
    float* row = out + (size_t)n * NC_;
    for (int i = threadIdx.x; i < V_ / 4; i += 256) {
        f32x4 v = *(const f32x4*)(row + i * 4);
        v[0] *= sc; v[1] *= sc; v[2] *= sc; v[3] *= sc;
        *(f32x4*)(row + i * 4) = v;
    }
}

// ---------------------------------------------------------------------------
// out[n, V+v] = sum_s attn[n,s]*copy[n] * src_map[s, n%B, v]
__global__ __launch_bounds__(128)
void k_copyattn(const float* __restrict__ attn, const float* __restrict__ src_map,
                const float* __restrict__ cvec, float* __restrict__ out)
{
    int n  = blockIdx.x;
    int bb = n & (B_ - 1);
    __shared__ float at[S_];
    float c = cvec[n];
    for (int i = threadIdx.x; i < S_; i += blockDim.x)
        at[i] = attn[(size_t)n * S_ + i] * c;
    __syncthreads();
    int v = threadIdx.x;
    if (v < CV_) {
        float s = 0.f;
#pragma unroll 4
        for (int si = 0; si < S_; ++si)
            s += at[si] * src_map[((size_t)si * B_ + bb) * CV_ + v];
        out[(size_t)n * NC_ + V_ + v] = s;
    }
}

// ---------------------------------------------------------------------------
extern "C" void kernel_launch(void* const* d_in, const int* in_sizes, int n_in,
                              void* d_out, int out_size, void* d_ws, size_t ws_size,
                              hipStream_t stream)
{
    const float* hidden  = (const float*)d_in[0];
    const float* attn    = (const float*)d_in[1];
    const float* src_map = (const float*)d_in[2];
    const float* W       = (const float*)d_in[3];
    const float* bias    = (const float*)d_in[4];
    const float* w_copy  = (const float*)d_in[5];
    const float* b_copy  = (const float*)d_in[6];
    float* out = (float*)d_out;

    float* cvec  = (float*)d_ws;          // [M_]
    float* scale = cvec + M_;             // [M_]

    k_copy<<<M_ / 4, 256, 0, stream>>>(hidden, w_copy, b_copy, cvec);

    dim3 gg((V_ + BN - 1) / BN, M_ / BM); // (391, 16)
    k_gemm_exp<<<gg, 256, 0, stream>>>(hidden, W, bias, out);

    k_rowsum<<<M_, 256, 0, stream>>>(out, cvec, scale);
    k_scale<<<M_, 256, 0, stream>>>(out, scale);
    k_copyattn<<<M_, 128, 0, stream>>>(attn, src_map, cvec, out);
}

// Round 2
// 653.921 us; speedup vs baseline: 1.3806x; 1.3806x over previous
//
#include <hip/hip_runtime.h>
#include <hip/hip_bf16.h>
#include <math.h>

// Problem constants
#define M_ 2048
#define K_ 1024
#define V_ 50000
#define VP_ 50048        // V padded to 128
#define CV_ 120
#define NC_ (V_ + CV_)   // 50120 out row stride
#define S_ 100
#define B_ 32
#define PAD_IDX_ 1

// GEMM tiling (m97-class structure)
#define BM 128
#define BN 128
#define BK 32

typedef float f32x4 __attribute__((ext_vector_type(4)));
typedef __bf16 bf16x4 __attribute__((ext_vector_type(4)));
typedef __bf16 bf16x8 __attribute__((ext_vector_type(8)));

__device__ __forceinline__ void async_copy16(const void* g, void* l) {
    __builtin_amdgcn_global_load_lds(
        (const __attribute__((address_space(1))) void*)g,
        (__attribute__((address_space(3))) void*)l, 16, 0, 0);
}

// ---------------------------------------------------------------------------
// hidden fp32 -> bf16 [M][K]
__global__ __launch_bounds__(256)
void k_h2b(const float* __restrict__ h, __bf16* __restrict__ o)
{
    size_t i = (size_t)(blockIdx.x * 256 + threadIdx.x) * 8;
    f32x4 a = *(const f32x4*)(h + i);
    f32x4 b = *(const f32x4*)(h + i + 4);
    bf16x8 v;
    v[0] = (__bf16)a[0]; v[1] = (__bf16)a[1]; v[2] = (__bf16)a[2]; v[3] = (__bf16)a[3];
    v[4] = (__bf16)b[0]; v[5] = (__bf16)b[1]; v[6] = (__bf16)b[2]; v[7] = (__bf16)b[3];
    *(bf16x8*)(o + i) = v;
}

// ---------------------------------------------------------------------------
// W [K][V] fp32 -> Wt [VP][K] bf16 (transpose + convert; pad rows zeroed)
__global__ __launch_bounds__(256)
void k_wt(const float* __restrict__ W, __bf16* __restrict__ Wt)
{
    __shared__ __bf16 t[64][72];
    int v0 = blockIdx.x * 64;   // 782 tiles
    int k0 = blockIdx.y * 64;   // 16 tiles
    int tid = threadIdx.x;
    int kr = tid >> 4;          // 0..15
    int vq = tid & 15;          // v-quad
    int v4 = v0 + vq * 4;
#pragma unroll
    for (int i = 0; i < 4; ++i) {
        int k = k0 + kr + i * 16;
        f32x4 val = {};
        if (v4 < V_) val = *(const f32x4*)(W + (size_t)k * V_ + v4);
#pragma unroll
        for (int c = 0; c < 4; ++c) t[vq * 4 + c][kr + i * 16] = (__bf16)val[c];
    }
    __syncthreads();
    int vr = tid >> 2;          // 0..63
    int q  = tid & 3;
    __bf16* dst = Wt + (size_t)(v0 + vr) * K_ + k0;
#pragma unroll
    for (int i = 0; i < 2; ++i) {
        bf16x8 o;
#pragma unroll
        for (int e = 0; e < 8; ++e) o[e] = t[vr][q * 8 + i * 32 + e];
        *(bf16x8*)(dst + q * 8 + i * 32) = o;
    }
}

// ---------------------------------------------------------------------------
// copy[n] = sigmoid(hidden[n,:] . w_copy + b_copy); also zero rowsum[n]
__global__ __launch_bounds__(256)
void k_copy(const float* __restrict__ hidden, const float* __restrict__ w_copy,
            const float* __restrict__ b_copy, float* __restrict__ cvec,
            float* __restrict__ rowsum)
{
    int n = blockIdx.x * 4 + (threadIdx.x >> 6);
    int lane = threadIdx.x & 63;
    const float* h = hidden + (size_t)n * K_;
    float s = 0.f;
#pragma unroll
    for (int i = 0; i < 4; ++i) {
        f32x4 hv = *(const f32x4*)(h + (lane + 64 * i) * 4);
        f32x4 wv = *(const f32x4*)(w_copy + (lane + 64 * i) * 4);
        s += hv[0] * wv[0] + hv[1] * wv[1] + hv[2] * wv[2] + hv[3] * wv[3];
    }
#pragma unroll
    for (int off = 32; off; off >>= 1) s += __shfl_down(s, off);
    if (lane == 0) {
        cvec[n] = 1.f / (1.f + __expf(-(s + b_copy[0])));
        rowsum[n] = 0.f;
    }
}

// ---------------------------------------------------------------------------
// GEMM: out[m,c] = exp(A[m,:] . Wt[c,:] + b[c]) (PAD col -> 0), + rowsum atomics
__global__ __launch_bounds__(256, 2)
void k_gemm_exp(const __bf16* __restrict__ A, const __bf16* __restrict__ Bt,
                const float* __restrict__ bias, float* __restrict__ out,
                float* __restrict__ rowsum)
{
    __shared__ __bf16 lA[BM * BK];
    __shared__ __bf16 lB[BN * BK];

    const int tid  = threadIdx.x;
    const int lane = tid & 63;
    const int wid  = tid >> 6;
    const int wm   = wid >> 1;
    const int wn   = wid & 1;

    const int m0 = blockIdx.x * BM;   // M fast -> concurrent blocks share W tile
    const int n0 = blockIdx.y * BN;

    f32x4 acc[4][4] = {};

    for (int k0 = 0; k0 < K_; k0 += BK) {
        // stage A: 512 granules of 16B, lane-linear LDS
#pragma unroll
        for (int j = 0; j < 2; ++j) {
            int g = j * 256 + tid;
            int row = g >> 2, gq = g & 3;
            async_copy16(A + (size_t)(m0 + row) * K_ + k0 + gq * 8,
                         &lA[(size_t)(j * 256 + wid * 64) * 8]);
        }
#pragma unroll
        for (int j = 0; j < 2; ++j) {
            int g = j * 256 + tid;
            int row = g >> 2, gq = g & 3;
            async_copy16(Bt + (size_t)(n0 + row) * K_ + k0 + gq * 8,
                         &lB[(size_t)(j * 256 + wid * 64) * 8]);
        }
        __syncthreads();

        bf16x8 fa[4], fb[4];
#pragma unroll
        for (int mf = 0; mf < 4; ++mf) {
            int row = wm * 64 + mf * 16 + (lane & 15);
            fa[mf] = *(const bf16x8*)(&lA[row * BK + (lane >> 4) * 8]);
        }
#pragma unroll
        for (int nf = 0; nf < 4; ++nf) {
            int row = wn * 64 + nf * 16 + (lane & 15);
            fb[nf] = *(const bf16x8*)(&lB[row * BK + (lane >> 4) * 8]);
        }
#pragma unroll
        for (int mf = 0; mf < 4; ++mf)
#pragma unroll
            for (int nf = 0; nf < 4; ++nf)
                acc[mf][nf] = __builtin_amdgcn_mfma_f32_16x16x32_bf16(
                    fa[mf], fb[nf], acc[mf][nf], 0, 0, 0);
        __syncthreads();
    }

    // epilogue: bias + exp + store + fused row-sum
    const int rbase = m0 + wm * 64;
    const int cbase = n0 + wn * 64;
    float psum[4][4] = {};   // [mf][r]
#pragma unroll
    for (int nf = 0; nf < 4; ++nf) {
        int gcol = cbase + nf * 16 + (lane & 15);
        bool live = (gcol < V_) && (gcol != PAD_IDX_);
        float bb = (gcol < V_) ? bias[gcol] : 0.f;
#pragma unroll
        for (int mf = 0; mf < 4; ++mf) {
#pragma unroll
            for (int r = 0; r < 4; ++r) {
                float e = live ? __expf(acc[mf][nf][r] + bb) : 0.f;
                psum[mf][r] += e;
                if (gcol < V_) {
                    int grow = rbase + mf * 16 + (lane >> 4) * 4 + r;
                    out[(size_t)grow * NC_ + gcol] = e;
                }
            }
        }
    }
#pragma unroll
    for (int off = 1; off < 16; off <<= 1)
#pragma unroll
        for (int mf = 0; mf < 4; ++mf)
#pragma unroll
            for (int r = 0; r < 4; ++r)
                psum[mf][r] += __shfl_xor(psum[mf][r], off);
    if ((lane & 15) == 0) {
#pragma unroll
        for (int mf = 0; mf < 4; ++mf)
#pragma unroll
            for (int r = 0; r < 4; ++r)
                atomicAdd(&rowsum[rbase + mf * 16 + (lane >> 4) * 4 + r],
                          psum[mf][r]);
    }
}

// ---------------------------------------------------------------------------
// out[n, 0:V] *= (1 - copy[n]) / rowsum[n]
__global__ __launch_bounds__(256)
void k_scale(float* __restrict__ out, const float* __restrict__ cvec,
             const float* __restrict__ rowsum)
{
    int n = blockIdx.x;
    float sc = (1.f - cvec[n]) / rowsum[n];
    float* row = out + (size_t)n * NC_;
    for (int i = threadIdx.x; i < V_ / 4; i += 256) {
        f32x4 v = *(const f32x4*)(row + i * 4);
        v[0] *= sc; v[1] *= sc; v[2] *= sc; v[3] *= sc;
        *(f32x4*)(row + i * 4) = v;
    }
}

// ---------------------------------------------------------------------------
// out[n, V+v] = sum_s attn[n,s]*copy[n] * src_map[s, n%B, v]
__global__ __launch_bounds__(128)
void k_copyattn(const float* __restrict__ attn, const float* __restrict__ src_map,
                const float* __restrict__ cvec, float* __restrict__ out)
{
    int n  = blockIdx.x;
    int bb = n & (B_ - 1);
    __shared__ float at[S_];
    float c = cvec[n];
    for (int i = threadIdx.x; i < S_; i += blockDim.x)
        at[i] = attn[(size_t)n * S_ + i] * c;
    __syncthreads();
    int v = threadIdx.x;
    if (v < CV_) {
        float s = 0.f;
#pragma unroll 4
        for (int si = 0; si < S_; ++si)
            s += at[si] * src_map[((size_t)si * B_ + bb) * CV_ + v];
        out[(size_t)n * NC_ + V_ + v] = s;
    }
}

// ---------------------------------------------------------------------------
extern "C" void kernel_launch(void* const* d_in, const int* in_sizes, int n_in,
                              void* d_out, int out_size, void* d_ws, size_t ws_size,
                              hipStream_t stream)
{
    const float* hidden  = (const float*)d_in[0];
    const float* attn    = (const float*)d_in[1];
    const float* src_map = (const float*)d_in[2];
    const float* W       = (const float*)d_in[3];
    const float* bias    = (const float*)d_in[4];
    const float* w_copy  = (const float*)d_in[5];
    const float* b_copy  = (const float*)d_in[6];
    float* out = (float*)d_out;

    // workspace layout
    __bf16* Wt = (__bf16*)d_ws;                         // [VP_][K_] bf16
    __bf16* Ab = (__bf16*)((char*)d_ws + (size_t)VP_ * K_ * 2);
    float* cvec   = (float*)((char*)d_ws + (size_t)VP_ * K_ * 2 + (size_t)M_ * K_ * 2);
    float* rowsum = cvec + M_;

    k_h2b<<<M_ * K_ / (256 * 8), 256, 0, stream>>>(hidden, Ab);
    k_wt<<<dim3(VP_ / 64, K_ / 64), 256, 0, stream>>>(W, Wt);
    k_copy<<<M_ / 4, 256, 0, stream>>>(hidden, w_copy, b_copy, cvec, rowsum);

    dim3 gg(M_ / BM, VP_ / BN);   // (16, 391), M fastest
    k_gemm_exp<<<gg, 256, 0, stream>>>(Ab, Wt, bias, out, rowsum);

    k_scale<<<M_, 256, 0, stream>>>(out, cvec, rowsum);
    k_copyattn<<<M_, 128, 0, stream>>>(attn, src_map, cvec, out);
}

// Round 3
// 628.990 us; speedup vs baseline: 1.4353x; 1.0396x over previous
//
#include <hip/hip_runtime.h>
#include <hip/hip_bf16.h>
#include <math.h>

// Problem constants
#define M_ 2048
#define K_ 1024
#define V_ 50000
#define VP_ 50048        // V padded to 128 (E row stride: 100096 B, 64B-aligned)
#define CV_ 120
#define NC_ (V_ + CV_)   // 50120 out row stride
#define S_ 100
#define B_ 32
#define PAD_IDX_ 1

// GEMM tiling
#define BM 128
#define BN 128
#define BK 32
#define NWG_ ((M_ / BM) * (VP_ / BN))   // 16 * 391 = 6256
#define WPX_ (NWG_ / 8)                 // 782 (exact)

typedef float f32x4 __attribute__((ext_vector_type(4)));
typedef __bf16 bf16x4 __attribute__((ext_vector_type(4)));
typedef __bf16 bf16x8 __attribute__((ext_vector_type(8)));
typedef unsigned short ushort;

__device__ __forceinline__ void async_copy16(const void* g, void* l) {
    __builtin_amdgcn_global_load_lds(
        (const __attribute__((address_space(1))) void*)g,
        (__attribute__((address_space(3))) void*)l, 16, 0, 0);
}
// k-granule swizzle: within each 4-granule (32-elem) block, XOR granule idx
// with s(row) = (row ^ (row>>2)) & 3  -> 2 lanes/bank on ds_read_b128 (free)
__device__ __forceinline__ int swz3(int row) { return (row ^ (row >> 2)) & 3; }

// ---------------------------------------------------------------------------
// fused: hidden->bf16 (k-swizzled), copy gate, rowsum zero. 1 wave per row.
__global__ __launch_bounds__(256)
void k_prep(const float* __restrict__ hidden, const float* __restrict__ w_copy,
            const float* __restrict__ b_copy, __bf16* __restrict__ Ab,
            float* __restrict__ cvec, float* __restrict__ rowsum)
{
    int n = blockIdx.x * 4 + (threadIdx.x >> 6);
    int lane = threadIdx.x & 63;
    const float* h = hidden + (size_t)n * K_;
    __bf16* arow = Ab + (size_t)n * K_;
    int sw = swz3(n);
    float s = 0.f;
#pragma unroll
    for (int g = 0; g < 2; ++g) {
        int gg = 2 * lane + g;            // granule 0..127 (8 elems each)
        f32x4 a = *(const f32x4*)(h + gg * 8);
        f32x4 b = *(const f32x4*)(h + gg * 8 + 4);
        f32x4 wa = *(const f32x4*)(w_copy + gg * 8);
        f32x4 wb = *(const f32x4*)(w_copy + gg * 8 + 4);
        s += a[0]*wa[0] + a[1]*wa[1] + a[2]*wa[2] + a[3]*wa[3]
           + b[0]*wb[0] + b[1]*wb[1] + b[2]*wb[2] + b[3]*wb[3];
        bf16x8 v;
        v[0]=(__bf16)a[0]; v[1]=(__bf16)a[1]; v[2]=(__bf16)a[2]; v[3]=(__bf16)a[3];
        v[4]=(__bf16)b[0]; v[5]=(__bf16)b[1]; v[6]=(__bf16)b[2]; v[7]=(__bf16)b[3];
        int gs = (gg & ~3) | ((gg & 3) ^ sw);
        *(bf16x8*)(arow + gs * 8) = v;
    }
#pragma unroll
    for (int off = 32; off; off >>= 1) s += __shfl_down(s, off);
    if (lane == 0) {
        cvec[n] = 1.f / (1.f + __expf(-(s + b_copy[0])));
        rowsum[n] = 0.f;
    }
}

// ---------------------------------------------------------------------------
// W [K][V] fp32 -> Wt [VP][K] bf16, transposed + k-swizzled; pad rows zeroed
__global__ __launch_bounds__(256)
void k_wt(const float* __restrict__ W, __bf16* __restrict__ Wt)
{
    __shared__ __bf16 t[64][72];
    int v0 = blockIdx.x * 64;
    int k0 = blockIdx.y * 64;
    int tid = threadIdx.x;
    int kr = tid >> 4;          // 0..15
    int vq = tid & 15;
    int v4 = v0 + vq * 4;
#pragma unroll
    for (int i = 0; i < 4; ++i) {
        int k = k0 + kr + i * 16;
        f32x4 val = {};
        if (v4 < V_) val = *(const f32x4*)(W + (size_t)k * V_ + v4);
#pragma unroll
        for (int c = 0; c < 4; ++c) t[vq * 4 + c][kr + i * 16] = (__bf16)val[c];
    }
    __syncthreads();
    int vr = tid >> 2;          // 0..63 local row
    int q  = tid & 3;
    int sw = swz3(v0 + vr);
    __bf16* dst = Wt + (size_t)(v0 + vr) * K_ + k0;
#pragma unroll
    for (int i = 0; i < 2; ++i) {
        bf16x8 o;
#pragma unroll
        for (int e = 0; e < 8; ++e) o[e] = t[vr][q * 8 + i * 32 + e];
        *(bf16x8*)(dst + i * 32 + (q ^ sw) * 8) = o;
    }
}

// ---------------------------------------------------------------------------
// one-hot src_map -> integer ids [S*B]
__global__ __launch_bounds__(256)
void k_ids(const float* __restrict__ src_map, int* __restrict__ ids)
{
    int i = blockIdx.x * 256 + threadIdx.x;
    if (i < S_ * B_) {
        const float* r = src_map + (size_t)i * CV_;
        int id = 0;
        for (int v = 0; v < CV_; ++v)
            if (r[v] > 0.5f) { id = v; break; }
        ids[i] = id;
    }
}

// ---------------------------------------------------------------------------
// GEMM: e = exp(A.Wt^T + b) (PAD col->0); store bf16 E (or fp32 out fallback);
// fused rowsum atomics. 2-phase prefetch, dbuf LDS, pre-swizzled operands.
template<bool E16>
__global__ __launch_bounds__(256, 3)
void k_gemm_exp(const __bf16* __restrict__ A, const __bf16* __restrict__ Bt,
                const float* __restrict__ bias, float* __restrict__ out,
                ushort* __restrict__ E, float* __restrict__ rowsum)
{
    __shared__ __bf16 lA[2][BM * BK];   // 8 KB per buf
    __shared__ __bf16 lB[2][BN * BK];

    const int tid  = threadIdx.x;
    const int lane = tid & 63;
    const int wid  = tid >> 6;
    const int wm   = wid >> 1;
    const int wn   = wid & 1;

    // bijective XCD swizzle: 6256 = 8 * 782
    int orig = blockIdx.y * (M_ / BM) + blockIdx.x;
    int nid  = (orig & 7) * WPX_ + (orig >> 3);
    const int m0 = (nid & 15) * BM;
    const int n0 = (nid >> 4) * BN;

    f32x4 acc[4][4] = {};

#define STAGE(buf, kt)                                                        \
    do {                                                                      \
        _Pragma("unroll")                                                     \
        for (int j = 0; j < 2; ++j) {                                         \
            int g = j * 256 + tid; int row = g >> 2, ch = g & 3;              \
            async_copy16(A + (size_t)(m0 + row) * K_ + (kt) * BK + ch * 8,    \
                         &lA[buf][(j * 256 + wid * 64) * 8]);                 \
        }                                                                     \
        _Pragma("unroll")                                                     \
        for (int j = 0; j < 2; ++j) {                                         \
            int g = j * 256 + tid; int row = g >> 2, ch = g & 3;              \
            async_copy16(Bt + (size_t)(n0 + row) * K_ + (kt) * BK + ch * 8,   \
                         &lB[buf][(j * 256 + wid * 64) * 8]);                 \
        }                                                                     \
    } while (0)

    STAGE(0, 0);
    __syncthreads();

    const int swl = (lane ^ (lane >> 2)) & 3;        // swz3 of (lane&15)
    const int chx = ((lane >> 4) ^ swl) * 8;         // swizzled chunk offset
    int cur = 0;
    for (int kt = 0; kt < K_ / BK; ++kt) {
        if (kt < K_ / BK - 1) STAGE(cur ^ 1, kt + 1);
        bf16x8 fa[4], fb[4];
#pragma unroll
        for (int mf = 0; mf < 4; ++mf)
            fa[mf] = *(const bf16x8*)(&lA[cur][(wm * 64 + mf * 16 + (lane & 15)) * BK + chx]);
#pragma unroll
        for (int nf = 0; nf < 4; ++nf)
            fb[nf] = *(const bf16x8*)(&lB[cur][(wn * 64 + nf * 16 + (lane & 15)) * BK + chx]);
#pragma unroll
        for (int mf = 0; mf < 4; ++mf)
#pragma unroll
            for (int nf = 0; nf < 4; ++nf)
                acc[mf][nf] = __builtin_amdgcn_mfma_f32_16x16x32_bf16(
                    fa[mf], fb[nf], acc[mf][nf], 0, 0, 0);
        __syncthreads();   // drains vmcnt(0): next tile staged
        cur ^= 1;
    }
#undef STAGE

    // epilogue: bias + exp + store + fused row-sum
    const int rbase = m0 + wm * 64;
    const int cbase = n0 + wn * 64;
    float psum[4][4] = {};
#pragma unroll
    for (int nf = 0; nf < 4; ++nf) {
        int gcol = cbase + nf * 16 + (lane & 15);
        bool live = (gcol < V_) && (gcol != PAD_IDX_);
        float bb = (gcol < V_) ? bias[gcol] : 0.f;
#pragma unroll
        for (int mf = 0; mf < 4; ++mf) {
#pragma unroll
            for (int r = 0; r < 4; ++r) {
                float e = live ? __expf(acc[mf][nf][r] + bb) : 0.f;
                psum[mf][r] += e;
                int grow = rbase + mf * 16 + (lane >> 4) * 4 + r;
                if (E16) {
                    __bf16 h = (__bf16)e;
                    __builtin_nontemporal_store(*(const ushort*)&h,
                                                &E[(size_t)grow * VP_ + gcol]);
                } else if (gcol < V_) {
                    out[(size_t)grow * NC_ + gcol] = e;
                }
            }
        }
    }
#pragma unroll
    for (int off = 1; off < 16; off <<= 1)
#pragma unroll
        for (int mf = 0; mf < 4; ++mf)
#pragma unroll
            for (int r = 0; r < 4; ++r)
                psum[mf][r] += __shfl_xor(psum[mf][r], off);
    if ((lane & 15) == 0) {
#pragma unroll
        for (int mf = 0; mf < 4; ++mf)
#pragma unroll
            for (int r = 0; r < 4; ++r)
                atomicAdd(&rowsum[rbase + mf * 16 + (lane >> 4) * 4 + r],
                          psum[mf][r]);
    }
}

// ---------------------------------------------------------------------------
// finish: out[n,0:V] = E[n,:] * (1-copy)/rowsum ; out[n,V:] = copy-scatter
template<bool E16>
__global__ __launch_bounds__(256)
void k_finish(const ushort* __restrict__ E, const float* __restrict__ cvec,
              const float* __restrict__ rowsum, const float* __restrict__ attn,
              const int* __restrict__ ids, float* __restrict__ out)
{
    int n = blockIdx.x;
    int tid = threadIdx.x;
    float c  = cvec[n];
    float sc = (1.f - c) / rowsum[n];
    float* row = out + (size_t)n * NC_;

    __shared__ float cp[CV_];
    if (tid < CV_) cp[tid] = 0.f;
    __syncthreads();
    if (tid < S_) atomicAdd(&cp[ids[tid * B_ + (n & (B_ - 1))]],
                            attn[(size_t)n * S_ + tid] * c);

    if (E16) {
        const ushort* e = E + (size_t)n * VP_;
        for (int i = tid; i < V_ / 8; i += 256) {
            bf16x8 v = __builtin_nontemporal_load((const bf16x8*)(e + i * 8));
            f32x4 o0, o1;
            o0[0]=(float)v[0]*sc; o0[1]=(float)v[1]*sc; o0[2]=(float)v[2]*sc; o0[3]=(float)v[3]*sc;
            o1[0]=(float)v[4]*sc; o1[1]=(float)v[5]*sc; o1[2]=(float)v[6]*sc; o1[3]=(float)v[7]*sc;
            __builtin_nontemporal_store(o0, (f32x4*)(row + i * 8));
            __builtin_nontemporal_store(o1, (f32x4*)(row + i * 8 + 4));
        }
    } else {
        for (int i = tid; i < V_ / 4; i += 256) {
            f32x4 v = *(const f32x4*)(row + i * 4);
            v[0]*=sc; v[1]*=sc; v[2]*=sc; v[3]*=sc;
            *(f32x4*)(row + i * 4) = v;
        }
    }
    __syncthreads();
    if (tid < CV_) row[V_ + tid] = cp[tid];
}

// ---------------------------------------------------------------------------
extern "C" void kernel_launch(void* const* d_in, const int* in_sizes, int n_in,
                              void* d_out, int out_size, void* d_ws, size_t ws_size,
                              hipStream_t stream)
{
    const float* hidden  = (const float*)d_in[0];
    const float* attn    = (const float*)d_in[1];
    const float* src_map = (const float*)d_in[2];
    const float* W       = (const float*)d_in[3];
    const float* bias    = (const float*)d_in[4];
    const float* w_copy  = (const float*)d_in[5];
    const float* b_copy  = (const float*)d_in[6];
    float* out = (float*)d_out;

    // workspace layout
    size_t off = 0;
    __bf16* Wt = (__bf16*)((char*)d_ws + off); off += (size_t)VP_ * K_ * 2;
    __bf16* Ab = (__bf16*)((char*)d_ws + off); off += (size_t)M_ * K_ * 2;
    float* cvec   = (float*)((char*)d_ws + off); off += M_ * 4;
    float* rowsum = (float*)((char*)d_ws + off); off += M_ * 4;
    int*   ids    = (int*)((char*)d_ws + off);   off += 16384;
    ushort* E     = (ushort*)((char*)d_ws + off);
    bool e16 = (off + (size_t)M_ * VP_ * 2) <= ws_size;

    k_prep<<<M_ / 4, 256, 0, stream>>>(hidden, w_copy, b_copy, Ab, cvec, rowsum);
    k_wt<<<dim3(VP_ / 64, K_ / 64), 256, 0, stream>>>(W, Wt);
    k_ids<<<(S_ * B_ + 255) / 256, 256, 0, stream>>>(src_map, ids);

    dim3 gg(M_ / BM, VP_ / BN);
    if (e16) {
        k_gemm_exp<true><<<gg, 256, 0, stream>>>(Ab, Wt, bias, out, E, rowsum);
        k_finish<true><<<M_, 256, 0, stream>>>(E, cvec, rowsum, attn, ids, out);
    } else {
        k_gemm_exp<false><<<gg, 256, 0, stream>>>(Ab, Wt, bias, out, E, rowsum);
        k_finish<false><<<M_, 256, 0, stream>>>((const ushort*)out, cvec, rowsum, attn, ids, out);
    }
}